// Round 1
// baseline (752.052 us; speedup 1.0000x reference)
//
#include <hip/hip_runtime.h>

// Problem: N=32, C=1024, B=1024
//   K = Wk@X[n] + Wk0 ; Q = Wq@X[n] + Wq0
//   Y[q,k] = (Q[:,q].K[:,k]) / sqrt(max(|Q_q|^2 |K_k|^2, 1e-12))
//   SM = softmax over q ; Z = X @ SM  -> [N,C,B] fp32
//
// All contractions cast to NT GEMM (both operands k-contiguous bf16),
// m97-style 128x128 tile, BK=32, global_load_lds(16B), mfma 16x16x32 bf16.

typedef __bf16 bf16x8 __attribute__((ext_vector_type(8)));
typedef __bf16 bf16x4 __attribute__((ext_vector_type(4)));
typedef float  f32x4  __attribute__((ext_vector_type(4)));

#define LOAD16_LDS(g, l)                                                       \
  __builtin_amdgcn_global_load_lds(                                            \
      (const __attribute__((address_space(1))) void*)(g),                      \
      (__attribute__((address_space(3))) void*)(l), 16, 0, 0)

// ---------------------------------------------------------------- converts
__global__ __launch_bounds__(256) void convert_w(
    const float* __restrict__ Wk, const float* __restrict__ Wq,
    const float* __restrict__ Wk0, const float* __restrict__ Wq0,
    __bf16* __restrict__ Wb, float* __restrict__ bias2) {
  int i = blockIdx.x * 256 + threadIdx.x;              // 0 .. 2M-1
  if (i < 1048576) Wb[i] = (__bf16)Wk[i];
  else             Wb[i] = (__bf16)Wq[i - 1048576];
  if (i < 1024) bias2[i] = Wk0[i];
  if (i >= 1048576 && i < 1048576 + 1024) bias2[1024 + (i - 1048576)] = Wq0[i - 1048576];
}

__global__ __launch_bounds__(256) void convert_x(
    const float* __restrict__ X, __bf16* __restrict__ Xb, __bf16* __restrict__ Xtb) {
  const int n = blockIdx.z;
  const int c0 = blockIdx.y * 32, b0 = blockIdx.x * 32;
  __shared__ float t[32][33];
  const int tx = threadIdx.x, ty = threadIdx.y;        // 32 x 8
  const float* Xn = X + (size_t)n * 1024 * 1024;
  __bf16* Xbn = Xb + (size_t)n * 1024 * 1024;
  __bf16* Xtn = Xtb + (size_t)n * 1024 * 1024;
#pragma unroll
  for (int i = 0; i < 4; ++i) {
    int c = c0 + ty + i * 8;
    float v = Xn[(size_t)c * 1024 + b0 + tx];
    Xbn[(size_t)c * 1024 + b0 + tx] = (__bf16)v;
    t[ty + i * 8][tx] = v;
  }
  __syncthreads();
#pragma unroll
  for (int i = 0; i < 4; ++i) {
    int b = b0 + ty + i * 8;
    Xtn[(size_t)b * 1024 + c0 + tx] = (__bf16)t[tx][ty + i * 8];
  }
}

// ---------------------------------------------------------------- NT GEMM
// C[m,n'] = sum_k A[m,k] * B[n',k]; A:[M][lda], B:[N][ldb], bf16 rows k-contig.
// EPI 0: bf16 out + bias[col]      (K/Q projection -> KQT)
// EPI 1: f32 out * rsqrt(max(rowS[m]*colS[n'],eps))  (Y^T)
// EPI 2: f32 out                    (Z)
template <int EPI>
__global__ __launch_bounds__(256) void gemm_nt(
    const __bf16* __restrict__ A, const __bf16* __restrict__ Bm,
    void* __restrict__ Out, int lda, int ldb, int ldo, int K,
    long long sA, long long sB, long long sO,
    const float* __restrict__ rowS, const float* __restrict__ colS,
    const float* __restrict__ bias) {
  const int n = blockIdx.z;
  A += (size_t)n * sA;
  Bm += (size_t)n * sB;
  const int tileM = blockIdx.y * 128, tileN = blockIdx.x * 128;

  __shared__ __bf16 Al[128 * 32];
  __shared__ __bf16 Bl[128 * 32];

  const int tid = threadIdx.x, w = tid >> 6, lane = tid & 63;
  const int srow = lane >> 2, scol = (lane & 3) * 8;   // staging: 16 rows x 32k per issue
  const int wr = (w >> 1) * 64, wc = (w & 1) * 64;     // 2x2 wave grid, 64x64 per wave
  const int r16 = lane & 15, quad = lane >> 4;

  f32x4 acc[4][4];
#pragma unroll
  for (int i = 0; i < 4; ++i)
#pragma unroll
    for (int j = 0; j < 4; ++j) acc[i][j] = (f32x4){0.f, 0.f, 0.f, 0.f};

  for (int k0 = 0; k0 < K; k0 += 32) {
#pragma unroll
    for (int i = 0; i < 2; ++i) {
      const __bf16* ga = A + (size_t)(tileM + w * 32 + i * 16 + srow) * lda + k0 + scol;
      LOAD16_LDS(ga, &Al[(w * 32 + i * 16) * 32]);
      const __bf16* gb = Bm + (size_t)(tileN + w * 32 + i * 16 + srow) * ldb + k0 + scol;
      LOAD16_LDS(gb, &Bl[(w * 32 + i * 16) * 32]);
    }
    __syncthreads();

    bf16x8 af[4], bf[4];
#pragma unroll
    for (int i = 0; i < 4; ++i)
      af[i] = *(const bf16x8*)&Al[(wr + i * 16 + r16) * 32 + quad * 8];
#pragma unroll
    for (int j = 0; j < 4; ++j)
      bf[j] = *(const bf16x8*)&Bl[(wc + j * 16 + r16) * 32 + quad * 8];
#pragma unroll
    for (int i = 0; i < 4; ++i)
#pragma unroll
      for (int j = 0; j < 4; ++j)
        acc[i][j] = __builtin_amdgcn_mfma_f32_16x16x32_bf16(af[i], bf[j], acc[i][j], 0, 0, 0);
    __syncthreads();
  }

#pragma unroll
  for (int i = 0; i < 4; ++i)
#pragma unroll
    for (int j = 0; j < 4; ++j)
#pragma unroll
      for (int t = 0; t < 4; ++t) {
        const int grow = tileM + wr + i * 16 + quad * 4 + t;
        const int gcol = tileN + wc + j * 16 + r16;
        const float v = acc[i][j][t];
        if (EPI == 0) {
          ((__bf16*)Out)[(size_t)n * sO + (size_t)grow * ldo + gcol] =
              (__bf16)(v + bias[gcol]);
        } else if (EPI == 1) {
          const float sc =
              rsqrtf(fmaxf(rowS[n * 1024 + grow] * colS[n * 1024 + gcol], 1e-12f));
          ((float*)Out)[(size_t)n * sO + (size_t)grow * ldo + gcol] = v * sc;
        } else {
          ((float*)Out)[(size_t)n * sO + (size_t)grow * ldo + gcol] = v;
        }
      }
}

// ------------------------------------------------- column norms (rows of KQT)
__global__ __launch_bounds__(256) void norms_kernel(
    const __bf16* __restrict__ KQT, float* __restrict__ DK2, float* __restrict__ DQ2) {
  const size_t row = blockIdx.x;                       // n*1024 + j
  const __bf16* p = KQT + row * 2048;
  const int t = threadIdx.x;
  float sk = 0.f, sq = 0.f;
#pragma unroll
  for (int i = 0; i < 4; ++i) {
    float vk = (float)p[i * 256 + t];
    float vq = (float)p[1024 + i * 256 + t];
    sk += vk * vk;
    sq += vq * vq;
  }
#pragma unroll
  for (int s = 32; s > 0; s >>= 1) {
    sk += __shfl_down(sk, s);
    sq += __shfl_down(sq, s);
  }
  __shared__ float rk[4], rq[4];
  const int lane = t & 63, w = t >> 6;
  if (lane == 0) { rk[w] = sk; rq[w] = sq; }
  __syncthreads();
  if (t == 0) {
    DK2[row] = rk[0] + rk[1] + rk[2] + rk[3];
    DQ2[row] = rq[0] + rq[1] + rq[2] + rq[3];
  }
}

// -------------------------------------------- softmax over contiguous rows of YT
__global__ __launch_bounds__(256) void softmax_kernel(
    const float* __restrict__ YT, __bf16* __restrict__ SMT) {
  const size_t row = blockIdx.x;
  const float4 v = ((const float4*)(YT + row * 1024))[threadIdx.x];
  float m = fmaxf(fmaxf(v.x, v.y), fmaxf(v.z, v.w));
#pragma unroll
  for (int s = 32; s > 0; s >>= 1) m = fmaxf(m, __shfl_down(m, s));
  __shared__ float red[4];
  __shared__ float bm, bs;
  const int lane = threadIdx.x & 63, w = threadIdx.x >> 6;
  if (lane == 0) red[w] = m;
  __syncthreads();
  if (threadIdx.x == 0) bm = fmaxf(fmaxf(red[0], red[1]), fmaxf(red[2], red[3]));
  __syncthreads();
  const float M = bm;
  const float e0 = __expf(v.x - M), e1 = __expf(v.y - M);
  const float e2 = __expf(v.z - M), e3 = __expf(v.w - M);
  float s4 = e0 + e1 + e2 + e3;
#pragma unroll
  for (int s = 32; s > 0; s >>= 1) s4 += __shfl_down(s4, s);
  if (lane == 0) red[w] = s4;
  __syncthreads();
  if (threadIdx.x == 0) bs = red[0] + red[1] + red[2] + red[3];
  __syncthreads();
  const float inv = 1.f / bs;
  bf16x4 o;
  o[0] = (__bf16)(e0 * inv);
  o[1] = (__bf16)(e1 * inv);
  o[2] = (__bf16)(e2 * inv);
  o[3] = (__bf16)(e3 * inv);
  ((bf16x4*)(SMT + row * 1024))[threadIdx.x] = o;
}

// ---------------------------------------------------------------- launch
extern "C" void kernel_launch(void* const* d_in, const int* in_sizes, int n_in,
                              void* d_out, int out_size, void* d_ws, size_t ws_size,
                              hipStream_t stream) {
  const float* X   = (const float*)d_in[0];
  const float* Wk  = (const float*)d_in[1];
  const float* Wq  = (const float*)d_in[2];
  const float* Wk0 = (const float*)d_in[3];
  const float* Wq0 = (const float*)d_in[4];

  char* ws = (char*)d_ws;
  const size_t MB = 1ull << 20;
  // layout (peak ~389 MB): SMT aliases Xtb (dead after GEMM1)
  __bf16* Xb   = (__bf16*)(ws);              //  64 MB  [N][C][B]
  __bf16* Xtb  = (__bf16*)(ws + 64 * MB);    //  64 MB  [N][B][C]
  __bf16* SMT  = (__bf16*)(ws + 64 * MB);    //  64 MB  alias   [N][Bk][Bq]
  __bf16* Wb   = (__bf16*)(ws + 128 * MB);   //   4 MB  [2C][C]
  __bf16* KQT  = (__bf16*)(ws + 132 * MB);   // 128 MB  [N][B][2C]  (K^T | Q^T)
  float*  YT   = (float*)(ws + 260 * MB);    // 128 MB  [N][Bk][Bq]
  float*  DK2  = (float*)(ws + 388 * MB);
  float*  DQ2  = (float*)(ws + 388 * MB + 256 * 1024);
  float*  bias2= (float*)(ws + 388 * MB + 512 * 1024);

  const long long M1 = 1024LL * 1024LL;

  convert_w<<<8192, 256, 0, stream>>>(Wk, Wq, Wk0, Wq0, Wb, bias2);
  convert_x<<<dim3(32, 32, 32), dim3(32, 8), 0, stream>>>(X, Xb, Xtb);

  // GEMM1: KQT[n][b][c2] = sum_d Xtb[n][b][d] * Wb[c2][d] + bias2[c2]
  gemm_nt<0><<<dim3(16, 8, 32), 256, 0, stream>>>(
      Xtb, Wb, KQT, 1024, 1024, 2048, 1024, M1, 0LL, 2 * M1, nullptr, nullptr, bias2);

  norms_kernel<<<32768, 256, 0, stream>>>(KQT, DK2, DQ2);

  // GEMM2: YT[n][k][q] = (K^T[k,:] . Q^T[q,:]) * rsqrt(max(DK2[k]*DQ2[q], eps))
  gemm_nt<1><<<dim3(8, 8, 32), 256, 0, stream>>>(
      KQT, KQT + 1024, YT, 2048, 2048, 1024, 1024, 2 * M1, 2 * M1, M1, DK2, DQ2, nullptr);

  softmax_kernel<<<32768, 256, 0, stream>>>(YT, SMT);

  // GEMM3: Z[n][c][j] = sum_q Xb[n][c][q] * SMT[n][j][q]
  gemm_nt<2><<<dim3(8, 8, 32), 256, 0, stream>>>(
      Xb, SMT, (float*)d_out, 1024, 1024, 1024, 1024, M1, M1, M1, nullptr, nullptr, nullptr);
}

// Round 2
// 745.382 us; speedup vs baseline: 1.0089x; 1.0089x over previous
//
#include <hip/hip_runtime.h>

// Problem: N=32, C=1024, B=1024
//   K = Wk@X[n] + Wk0 ; Q = Wq@X[n] + Wq0
//   Y[q,k] = (Q[:,q].K[:,k]) / sqrt(max(|Q_q|^2 |K_k|^2, 1e-12))
//   SM = softmax over q ; Z = X @ SM  -> [N,C,B] fp32
//
// NT GEMM (both operands k-contiguous bf16), 128x128 tile, BK=32,
// global_load_lds(16B) with XOR-swizzled LDS layout (conflict-free reads),
// mfma 16x16x32 bf16. Norms fused into GEMM1 epilogue (atomicAdd).

typedef __bf16 bf16x8 __attribute__((ext_vector_type(8)));
typedef __bf16 bf16x4 __attribute__((ext_vector_type(4)));
typedef float  f32x4  __attribute__((ext_vector_type(4)));

#define LOAD16_LDS(g, l)                                                       \
  __builtin_amdgcn_global_load_lds(                                            \
      (const __attribute__((address_space(1))) void*)(g),                      \
      (__attribute__((address_space(3))) void*)(l), 16, 0, 0)

// ---------------------------------------------------------------- converts
__global__ __launch_bounds__(256) void convert_w(
    const float* __restrict__ Wk, const float* __restrict__ Wq,
    const float* __restrict__ Wk0, const float* __restrict__ Wq0,
    __bf16* __restrict__ Wb, float* __restrict__ bias2) {
  int i = blockIdx.x * 256 + threadIdx.x;              // 0 .. 2M-1
  if (i < 1048576) Wb[i] = (__bf16)Wk[i];
  else             Wb[i] = (__bf16)Wq[i - 1048576];
  if (i < 1024) bias2[i] = Wk0[i];
  if (i >= 1048576 && i < 1048576 + 1024) bias2[1024 + (i - 1048576)] = Wq0[i - 1048576];
}

__global__ __launch_bounds__(256) void convert_x(
    const float* __restrict__ X, __bf16* __restrict__ Xb, __bf16* __restrict__ Xtb) {
  const int n = blockIdx.z;
  const int c0 = blockIdx.y * 32, b0 = blockIdx.x * 32;
  __shared__ float t[32][33];
  const int tx = threadIdx.x, ty = threadIdx.y;        // 32 x 8
  const float* Xn = X + (size_t)n * 1024 * 1024;
  __bf16* Xbn = Xb + (size_t)n * 1024 * 1024;
  __bf16* Xtn = Xtb + (size_t)n * 1024 * 1024;
#pragma unroll
  for (int i = 0; i < 4; ++i) {
    int c = c0 + ty + i * 8;
    float v = Xn[(size_t)c * 1024 + b0 + tx];
    Xbn[(size_t)c * 1024 + b0 + tx] = (__bf16)v;
    t[ty + i * 8][tx] = v;
  }
  __syncthreads();
#pragma unroll
  for (int i = 0; i < 4; ++i) {
    int b = b0 + ty + i * 8;
    Xtn[(size_t)b * 1024 + c0 + tx] = (__bf16)t[tx][ty + i * 8];
  }
}

// ---------------------------------------------------------------- NT GEMM
// C[m,n'] = sum_k A[m,k] * B[n',k]; A:[M][lda], B:[N][ldb], bf16 rows k-contig.
// LDS layout is XOR-swizzled: element (row r, 8-col-block c) lives at
// byte offset r*64 + (c ^ ((r>>1)&3))*16.  Staging picks the matching
// global column per lane so global_load_lds (lane-contiguous dest) lands
// each 16B chunk in its swizzled slot.  Read side: 16 lanes of a quad
// group spread over 8 bank-starts -> 2-way aliasing (free).
// EPI 0: bf16 out + bias[col]; fused per-row sum-of-squares -> atomicAdd
// EPI 1: f32 out * rsqrt(max(rowS[m]*colS[n'],eps))  (Y^T)
// EPI 2: f32 out                                      (Z)
template <int EPI>
__global__ __launch_bounds__(256) void gemm_nt(
    const __bf16* __restrict__ A, const __bf16* __restrict__ Bm,
    void* __restrict__ Out, int lda, int ldb, int ldo, int K,
    long long sA, long long sB, long long sO,
    const float* __restrict__ rowS, const float* __restrict__ colS,
    const float* __restrict__ bias,
    float* __restrict__ sqK, float* __restrict__ sqQ) {
  const int n = blockIdx.z;
  A += (size_t)n * sA;
  Bm += (size_t)n * sB;
  const int tileM = blockIdx.y * 128, tileN = blockIdx.x * 128;

  __shared__ __bf16 Al[128 * 32];
  __shared__ __bf16 Bl[128 * 32];

  const int tid = threadIdx.x, w = tid >> 6, lane = tid & 63;
  const int srow = lane >> 2;                           // 0..15 within group
  const int scol = ((lane & 3) ^ ((srow >> 1) & 3)) * 8; // swizzled source col
  const int wr = (w >> 1) * 64, wc = (w & 1) * 64;      // 2x2 wave grid
  const int r16 = lane & 15, quad = lane >> 4;

  // staging pointers (hoisted; advance by 32 elems per K-iter)
  const __bf16* gA0 = A + (size_t)(tileM + w * 32 + srow) * lda + scol;
  const __bf16* gA1 = gA0 + (size_t)16 * lda;
  const __bf16* gB0 = Bm + (size_t)(tileN + w * 32 + srow) * ldb + scol;
  const __bf16* gB1 = gB0 + (size_t)16 * ldb;
  __bf16* lA0 = &Al[(w * 32) * 32];
  __bf16* lA1 = &Al[(w * 32 + 16) * 32];
  __bf16* lB0 = &Bl[(w * 32) * 32];
  __bf16* lB1 = &Bl[(w * 32 + 16) * 32];

  f32x4 acc[4][4];
#pragma unroll
  for (int i = 0; i < 4; ++i)
#pragma unroll
    for (int j = 0; j < 4; ++j) acc[i][j] = (f32x4){0.f, 0.f, 0.f, 0.f};

  for (int k0 = 0; k0 < K; k0 += 32) {
    LOAD16_LDS(gA0, lA0);
    LOAD16_LDS(gA1, lA1);
    LOAD16_LDS(gB0, lB0);
    LOAD16_LDS(gB1, lB1);
    gA0 += 32; gA1 += 32; gB0 += 32; gB1 += 32;
    __syncthreads();

    bf16x8 af[4], bf[4];
#pragma unroll
    for (int i = 0; i < 4; ++i) {
      const int r = wr + i * 16 + r16;
      af[i] = *(const bf16x8*)&Al[r * 32 + ((quad ^ ((r >> 1) & 3)) * 8)];
    }
#pragma unroll
    for (int j = 0; j < 4; ++j) {
      const int r = wc + j * 16 + r16;
      bf[j] = *(const bf16x8*)&Bl[r * 32 + ((quad ^ ((r >> 1) & 3)) * 8)];
    }
#pragma unroll
    for (int i = 0; i < 4; ++i)
#pragma unroll
      for (int j = 0; j < 4; ++j)
        acc[i][j] = __builtin_amdgcn_mfma_f32_16x16x32_bf16(af[i], bf[j], acc[i][j], 0, 0, 0);
    __syncthreads();
  }

  if (EPI == 0) {
    // store bf16 (+bias) and accumulate per-row sum of squares of the
    // ROUNDED values (matches what GEMM2 will read).
    float* sq = (tileN < 1024) ? sqK : sqQ;
#pragma unroll
    for (int i = 0; i < 4; ++i) {
#pragma unroll
      for (int t = 0; t < 4; ++t) {
        const int grow = tileM + wr + i * 16 + quad * 4 + t;
        float ss = 0.f;
#pragma unroll
        for (int j = 0; j < 4; ++j) {
          const int gcol = tileN + wc + j * 16 + r16;
          const __bf16 bv = (__bf16)(acc[i][j][t] + bias[gcol]);
          ((__bf16*)Out)[(size_t)n * sO + (size_t)grow * ldo + gcol] = bv;
          const float f = (float)bv;
          ss += f * f;
        }
        ss += __shfl_xor(ss, 1);
        ss += __shfl_xor(ss, 2);
        ss += __shfl_xor(ss, 4);
        ss += __shfl_xor(ss, 8);
        if (r16 == 0) atomicAdd(&sq[n * 1024 + grow], ss);
      }
    }
  } else {
#pragma unroll
    for (int i = 0; i < 4; ++i)
#pragma unroll
      for (int j = 0; j < 4; ++j)
#pragma unroll
        for (int t = 0; t < 4; ++t) {
          const int grow = tileM + wr + i * 16 + quad * 4 + t;
          const int gcol = tileN + wc + j * 16 + r16;
          const float v = acc[i][j][t];
          if (EPI == 1) {
            const float sc =
                rsqrtf(fmaxf(rowS[n * 1024 + grow] * colS[n * 1024 + gcol], 1e-12f));
            ((float*)Out)[(size_t)n * sO + (size_t)grow * ldo + gcol] = v * sc;
          } else {
            ((float*)Out)[(size_t)n * sO + (size_t)grow * ldo + gcol] = v;
          }
        }
  }
}

// -------------------------------------------- softmax over contiguous rows of YT
__global__ __launch_bounds__(256) void softmax_kernel(
    const float* __restrict__ YT, __bf16* __restrict__ SMT) {
  const size_t row = blockIdx.x;
  const float4 v = ((const float4*)(YT + row * 1024))[threadIdx.x];
  float m = fmaxf(fmaxf(v.x, v.y), fmaxf(v.z, v.w));
#pragma unroll
  for (int s = 32; s > 0; s >>= 1) m = fmaxf(m, __shfl_down(m, s));
  __shared__ float red[4];
  __shared__ float bm, bs;
  const int lane = threadIdx.x & 63, w = threadIdx.x >> 6;
  if (lane == 0) red[w] = m;
  __syncthreads();
  if (threadIdx.x == 0) bm = fmaxf(fmaxf(red[0], red[1]), fmaxf(red[2], red[3]));
  __syncthreads();
  const float M = bm;
  const float e0 = __expf(v.x - M), e1 = __expf(v.y - M);
  const float e2 = __expf(v.z - M), e3 = __expf(v.w - M);
  float s4 = e0 + e1 + e2 + e3;
#pragma unroll
  for (int s = 32; s > 0; s >>= 1) s4 += __shfl_down(s4, s);
  if (lane == 0) red[w] = s4;
  __syncthreads();
  if (threadIdx.x == 0) bs = red[0] + red[1] + red[2] + red[3];
  __syncthreads();
  const float inv = 1.f / bs;
  bf16x4 o;
  o[0] = (__bf16)(e0 * inv);
  o[1] = (__bf16)(e1 * inv);
  o[2] = (__bf16)(e2 * inv);
  o[3] = (__bf16)(e3 * inv);
  ((bf16x4*)(SMT + row * 1024))[threadIdx.x] = o;
}

// ---------------------------------------------------------------- launch
extern "C" void kernel_launch(void* const* d_in, const int* in_sizes, int n_in,
                              void* d_out, int out_size, void* d_ws, size_t ws_size,
                              hipStream_t stream) {
  const float* X   = (const float*)d_in[0];
  const float* Wk  = (const float*)d_in[1];
  const float* Wq  = (const float*)d_in[2];
  const float* Wk0 = (const float*)d_in[3];
  const float* Wq0 = (const float*)d_in[4];

  char* ws = (char*)d_ws;
  const size_t MB = 1ull << 20;
  // layout (peak ~389 MB): SMT aliases Xtb (dead after GEMM1)
  __bf16* Xb   = (__bf16*)(ws);              //  64 MB  [N][C][B]
  __bf16* Xtb  = (__bf16*)(ws + 64 * MB);    //  64 MB  [N][B][C]
  __bf16* SMT  = (__bf16*)(ws + 64 * MB);    //  64 MB  alias   [N][Bk][Bq]
  __bf16* Wb   = (__bf16*)(ws + 128 * MB);   //   4 MB  [2C][C]
  __bf16* KQT  = (__bf16*)(ws + 132 * MB);   // 128 MB  [N][B][2C]  (K^T | Q^T)
  float*  YT   = (float*)(ws + 260 * MB);    // 128 MB  [N][Bk][Bq]
  float*  DK2  = (float*)(ws + 388 * MB);
  float*  DQ2  = (float*)(ws + 388 * MB + 256 * 1024);
  float*  bias2= (float*)(ws + 388 * MB + 512 * 1024);

  const long long M1 = 1024LL * 1024LL;

  hipMemsetAsync(DK2, 0, 2 * 256 * 1024, stream);  // zero DK2+DQ2 (atomic targets)

  convert_w<<<8192, 256, 0, stream>>>(Wk, Wq, Wk0, Wq0, Wb, bias2);
  convert_x<<<dim3(32, 32, 32), dim3(32, 8), 0, stream>>>(X, Xb, Xtb);

  // GEMM1: KQT[n][b][c2] = sum_d Xtb[n][b][d] * Wb[c2][d] + bias2[c2]
  //        fused: DK2[n][b] = sum_{c<1024} K^2, DQ2[n][b] = sum Q^2
  gemm_nt<0><<<dim3(16, 8, 32), 256, 0, stream>>>(
      Xtb, Wb, KQT, 1024, 1024, 2048, 1024, M1, 0LL, 2 * M1,
      nullptr, nullptr, bias2, DK2, DQ2);

  // GEMM2: YT[n][k][q] = (K^T[k,:] . Q^T[q,:]) * rsqrt(max(DK2[k]*DQ2[q], eps))
  gemm_nt<1><<<dim3(8, 8, 32), 256, 0, stream>>>(
      KQT, KQT + 1024, YT, 2048, 2048, 1024, 1024, 2 * M1, 2 * M1, M1,
      DK2, DQ2, nullptr, nullptr, nullptr);

  softmax_kernel<<<32768, 256, 0, stream>>>(YT, SMT);

  // GEMM3: Z[n][c][j] = sum_q Xb[n][c][q] * SMT[n][j][q]
  gemm_nt<2><<<dim3(8, 8, 32), 256, 0, stream>>>(
      Xb, SMT, (float*)d_out, 1024, 1024, 1024, 1024, M1, M1, M1,
      nullptr, nullptr, nullptr, nullptr, nullptr);
}

// Round 3
// 694.852 us; speedup vs baseline: 1.0823x; 1.0727x over previous
//
#include <hip/hip_runtime.h>

// Problem: N=32, C=1024, B=1024
//   K = Wk@X[n] + Wk0 ; Q = Wq@X[n] + Wq0
//   Y[q,k] = (Q[:,q].K[:,k]) / sqrt(max(|Q_q|^2 |K_k|^2, 1e-12))
//   SM = softmax over q ; Z = X @ SM  -> [N,C,B] fp32
//
// NT GEMM (both operands k-contiguous bf16), 128x128 tile, BK=32,
// global_load_lds(16B), XOR-swizzled LDS, mfma 16x16x32 bf16.
// Norms fused into GEMM1 epilogue. Softmax fused into GEMM2/GEMM3:
// |Y|<=1 (cosine) so exp uses fixed shift M=1 (no max pass); the
// normalizer 1/S factors out of Z and is applied in GEMM3's epilogue.

typedef __bf16 bf16x8 __attribute__((ext_vector_type(8)));
typedef float  f32x4  __attribute__((ext_vector_type(4)));

#define LOAD16_LDS(g, l)                                                       \
  __builtin_amdgcn_global_load_lds(                                            \
      (const __attribute__((address_space(1))) void*)(g),                      \
      (__attribute__((address_space(3))) void*)(l), 16, 0, 0)

// ---------------------------------------------------------------- converts
__global__ __launch_bounds__(256) void convert_w(
    const float* __restrict__ Wk, const float* __restrict__ Wq,
    const float* __restrict__ Wk0, const float* __restrict__ Wq0,
    __bf16* __restrict__ Wb, float* __restrict__ bias2) {
  int i = blockIdx.x * 256 + threadIdx.x;              // 0 .. 2M-1
  if (i < 1048576) Wb[i] = (__bf16)Wk[i];
  else             Wb[i] = (__bf16)Wq[i - 1048576];
  if (i < 1024) bias2[i] = Wk0[i];
  if (i >= 1048576 && i < 1048576 + 1024) bias2[1024 + (i - 1048576)] = Wq0[i - 1048576];
}

__global__ __launch_bounds__(256) void convert_x(
    const float* __restrict__ X, __bf16* __restrict__ Xb, __bf16* __restrict__ Xtb) {
  const int n = blockIdx.z;
  const int c0 = blockIdx.y * 32, b0 = blockIdx.x * 32;
  __shared__ float t[32][33];
  const int tx = threadIdx.x, ty = threadIdx.y;        // 32 x 8
  const float* Xn = X + (size_t)n * 1024 * 1024;
  __bf16* Xbn = Xb + (size_t)n * 1024 * 1024;
  __bf16* Xtn = Xtb + (size_t)n * 1024 * 1024;
#pragma unroll
  for (int i = 0; i < 4; ++i) {
    int c = c0 + ty + i * 8;
    float v = Xn[(size_t)c * 1024 + b0 + tx];
    Xbn[(size_t)c * 1024 + b0 + tx] = (__bf16)v;
    t[ty + i * 8][tx] = v;
  }
  __syncthreads();
#pragma unroll
  for (int i = 0; i < 4; ++i) {
    int b = b0 + ty + i * 8;
    Xtn[(size_t)b * 1024 + c0 + tx] = (__bf16)t[tx][ty + i * 8];
  }
}

// ---------------------------------------------------------------- NT GEMM
// C[m,n'] = sum_k A[m,k] * B[n',k]; A:[M][lda], B:[N][ldb], bf16 rows k-contig.
// LDS XOR-swizzle: (row r, 16B block c) at byte r*64 + (c ^ ((r>>1)&3))*16.
// EPI 0: bf16 out + bias[col]; fused per-row sum-of-squares -> atomicAdd
// EPI 1: e = exp(v*rsqrt(max(rowS*colS,eps)) - 1) bf16 out; row-sum -> sqK
// EPI 2: f32 out * (1/colS[col])                   (Z, softmax normalizer)
template <int EPI>
__global__ __launch_bounds__(256) void gemm_nt(
    const __bf16* __restrict__ A, const __bf16* __restrict__ Bm,
    void* __restrict__ Out, int lda, int ldb, int ldo, int K,
    long long sA, long long sB, long long sO,
    const float* __restrict__ rowS, const float* __restrict__ colS,
    const float* __restrict__ bias,
    float* __restrict__ sqK, float* __restrict__ sqQ) {
  const int n = blockIdx.z;
  A += (size_t)n * sA;
  Bm += (size_t)n * sB;
  const int tileM = blockIdx.y * 128, tileN = blockIdx.x * 128;

  __shared__ __bf16 Al[128 * 32];
  __shared__ __bf16 Bl[128 * 32];

  const int tid = threadIdx.x, w = tid >> 6, lane = tid & 63;
  const int srow = lane >> 2;                            // 0..15
  const int scol = ((lane & 3) ^ ((srow >> 1) & 3)) * 8; // swizzled source col
  const int wr = (w >> 1) * 64, wc = (w & 1) * 64;       // 2x2 wave grid
  const int r16 = lane & 15, quad = lane >> 4;

  const __bf16* gA0 = A + (size_t)(tileM + w * 32 + srow) * lda + scol;
  const __bf16* gA1 = gA0 + (size_t)16 * lda;
  const __bf16* gB0 = Bm + (size_t)(tileN + w * 32 + srow) * ldb + scol;
  const __bf16* gB1 = gB0 + (size_t)16 * ldb;
  __bf16* lA0 = &Al[(w * 32) * 32];
  __bf16* lA1 = &Al[(w * 32 + 16) * 32];
  __bf16* lB0 = &Bl[(w * 32) * 32];
  __bf16* lB1 = &Bl[(w * 32 + 16) * 32];

  f32x4 acc[4][4];
#pragma unroll
  for (int i = 0; i < 4; ++i)
#pragma unroll
    for (int j = 0; j < 4; ++j) acc[i][j] = (f32x4){0.f, 0.f, 0.f, 0.f};

  for (int k0 = 0; k0 < K; k0 += 32) {
    LOAD16_LDS(gA0, lA0);
    LOAD16_LDS(gA1, lA1);
    LOAD16_LDS(gB0, lB0);
    LOAD16_LDS(gB1, lB1);
    gA0 += 32; gA1 += 32; gB0 += 32; gB1 += 32;
    __syncthreads();

    bf16x8 af[4], bf[4];
#pragma unroll
    for (int i = 0; i < 4; ++i) {
      const int r = wr + i * 16 + r16;
      af[i] = *(const bf16x8*)&Al[r * 32 + ((quad ^ ((r >> 1) & 3)) * 8)];
    }
#pragma unroll
    for (int j = 0; j < 4; ++j) {
      const int r = wc + j * 16 + r16;
      bf[j] = *(const bf16x8*)&Bl[r * 32 + ((quad ^ ((r >> 1) & 3)) * 8)];
    }
#pragma unroll
    for (int i = 0; i < 4; ++i)
#pragma unroll
      for (int j = 0; j < 4; ++j)
        acc[i][j] = __builtin_amdgcn_mfma_f32_16x16x32_bf16(af[i], bf[j], acc[i][j], 0, 0, 0);
    __syncthreads();
  }

  if (EPI == 0) {
    // bf16 store (+bias) and per-row sum of squares of the ROUNDED values.
    float* sq = (tileN < 1024) ? sqK : sqQ;
#pragma unroll
    for (int i = 0; i < 4; ++i) {
#pragma unroll
      for (int t = 0; t < 4; ++t) {
        const int grow = tileM + wr + i * 16 + quad * 4 + t;
        float ss = 0.f;
#pragma unroll
        for (int j = 0; j < 4; ++j) {
          const int gcol = tileN + wc + j * 16 + r16;
          const __bf16 bv = (__bf16)(acc[i][j][t] + bias[gcol]);
          ((__bf16*)Out)[(size_t)n * sO + (size_t)grow * ldo + gcol] = bv;
          const float f = (float)bv;
          ss += f * f;
        }
        ss += __shfl_xor(ss, 1);
        ss += __shfl_xor(ss, 2);
        ss += __shfl_xor(ss, 4);
        ss += __shfl_xor(ss, 8);
        if (r16 == 0) atomicAdd(&sq[n * 1024 + grow], ss);
      }
    }
  } else if (EPI == 1) {
    // e = exp(y - 1), y = cosine in [-1,1] -> no max pass needed.
    float cs[4];
#pragma unroll
    for (int j = 0; j < 4; ++j)
      cs[j] = colS[n * 1024 + tileN + wc + j * 16 + r16];
#pragma unroll
    for (int i = 0; i < 4; ++i) {
#pragma unroll
      for (int t = 0; t < 4; ++t) {
        const int grow = tileM + wr + i * 16 + quad * 4 + t;
        const float rs = rowS[n * 1024 + grow];
        float ss = 0.f;
#pragma unroll
        for (int j = 0; j < 4; ++j) {
          const int gcol = tileN + wc + j * 16 + r16;
          const float y = acc[i][j][t] * rsqrtf(fmaxf(rs * cs[j], 1e-12f));
          const __bf16 e = (__bf16)__expf(y - 1.0f);
          ((__bf16*)Out)[(size_t)n * sO + (size_t)grow * ldo + gcol] = e;
          ss += (float)e;
        }
        ss += __shfl_xor(ss, 1);
        ss += __shfl_xor(ss, 2);
        ss += __shfl_xor(ss, 4);
        ss += __shfl_xor(ss, 8);
        if (r16 == 0) atomicAdd(&sqK[n * 1024 + grow], ss);
      }
    }
  } else {
    float inv[4];
#pragma unroll
    for (int j = 0; j < 4; ++j)
      inv[j] = 1.0f / colS[n * 1024 + tileN + wc + j * 16 + r16];
#pragma unroll
    for (int i = 0; i < 4; ++i)
#pragma unroll
      for (int j = 0; j < 4; ++j)
#pragma unroll
        for (int t = 0; t < 4; ++t) {
          const int grow = tileM + wr + i * 16 + quad * 4 + t;
          const int gcol = tileN + wc + j * 16 + r16;
          ((float*)Out)[(size_t)n * sO + (size_t)grow * ldo + gcol] =
              acc[i][j][t] * inv[j];
        }
  }
}

// ---------------------------------------------------------------- launch
extern "C" void kernel_launch(void* const* d_in, const int* in_sizes, int n_in,
                              void* d_out, int out_size, void* d_ws, size_t ws_size,
                              hipStream_t stream) {
  const float* X   = (const float*)d_in[0];
  const float* Wk  = (const float*)d_in[1];
  const float* Wq  = (const float*)d_in[2];
  const float* Wk0 = (const float*)d_in[3];
  const float* Wq0 = (const float*)d_in[4];

  char* ws = (char*)d_ws;
  const size_t MB = 1ull << 20;
  // layout (peak ~261 MB): ET aliases Xtb (dead after GEMM1)
  __bf16* Xb   = (__bf16*)(ws);              //  64 MB  [N][C][B]
  __bf16* Xtb  = (__bf16*)(ws + 64 * MB);    //  64 MB  [N][B][C]
  __bf16* ET   = (__bf16*)(ws + 64 * MB);    //  64 MB  alias   [N][Bk][Bq]
  __bf16* Wb   = (__bf16*)(ws + 128 * MB);   //   4 MB  [2C][C]
  __bf16* KQT  = (__bf16*)(ws + 132 * MB);   // 128 MB  [N][B][2C]  (K^T | Q^T)
  float*  DK2  = (float*)(ws + 260 * MB);            // 128 KB
  float*  DQ2  = (float*)(ws + 260 * MB + 128 * 1024);
  float*  S    = (float*)(ws + 260 * MB + 256 * 1024); // ET row sums
  float*  bias2= (float*)(ws + 260 * MB + 384 * 1024);

  const long long M1 = 1024LL * 1024LL;

  hipMemsetAsync(DK2, 0, 3 * 128 * 1024, stream);  // zero DK2, DQ2, S

  convert_w<<<8192, 256, 0, stream>>>(Wk, Wq, Wk0, Wq0, Wb, bias2);
  convert_x<<<dim3(32, 32, 32), dim3(32, 8), 0, stream>>>(X, Xb, Xtb);

  // GEMM1: KQT[n][b][c2] = sum_d Xtb[n][b][d] * Wb[c2][d] + bias2[c2]
  //        fused: DK2[n][b] = sum K^2, DQ2[n][b] = sum Q^2
  gemm_nt<0><<<dim3(16, 8, 32), 256, 0, stream>>>(
      Xtb, Wb, KQT, 1024, 1024, 2048, 1024, M1, 0LL, 2 * M1,
      nullptr, nullptr, bias2, DK2, DQ2);

  // GEMM2: ET[n][k][q] = exp(cos(K_k,Q_q) - 1)  (bf16), S[n][k] = row sums
  gemm_nt<1><<<dim3(8, 8, 32), 256, 0, stream>>>(
      KQT, KQT + 1024, ET, 2048, 2048, 1024, 1024, 2 * M1, 2 * M1, M1,
      DK2, DQ2, nullptr, S, nullptr);

  // GEMM3: Z[n][c][j] = (sum_q Xb[n][c][q] * ET[n][j][q]) / S[n][j]
  gemm_nt<2><<<dim3(8, 8, 32), 256, 0, stream>>>(
      Xb, ET, (float*)d_out, 1024, 1024, 1024, 1024, M1, M1, M1,
      nullptr, S, nullptr, nullptr, nullptr);
}